// Round 2
// baseline (763.451 us; speedup 1.0000x reference)
//
#include <hip/hip_runtime.h>
#include <cstdint>

#define AS1 __attribute__((address_space(1)))
#define AS3 __attribute__((address_space(3)))

typedef __attribute__((ext_vector_type(8))) short short8;
typedef __attribute__((ext_vector_type(4))) float floatx4;
typedef unsigned short u16;

static constexpr int NN   = 100000;
static constexpr int FF   = 512;
static constexpr int HH   = 128;
static constexpr int EE   = 1600000;
static constexpr int PADM = 100096;   // 782 * 128
static constexpr int NPAD = 100352;   // 98 * 1024, scan padding
static constexpr int NB   = 98;       // scan blocks

__device__ __forceinline__ u16 f2bf_rne(float v) {
    uint32_t u = __builtin_bit_cast(uint32_t, v);
    u += 0x7fffu + ((u >> 16) & 1u);
    return (u16)(u >> 16);
}
__device__ __forceinline__ float bf2f(u16 h) {
    uint32_t u = ((uint32_t)h) << 16;
    return __builtin_bit_cast(float, u);
}
__device__ __forceinline__ void async16(const void* g, void* l) {
    __builtin_amdgcn_global_load_lds((AS1 const void*)g, (AS3 void*)l, 16, 0, 0);
}

// ---- split features into bf16 hi + lo --------------------------------------
__global__ void k_split_a(const float* __restrict__ A,
                          u16* __restrict__ hi, u16* __restrict__ lo) {
    int t = blockIdx.x * 256 + threadIdx.x;           // t < NN*FF/4
    float4 x = ((const float4*)A)[t];
    u16 h0 = f2bf_rne(x.x), h1 = f2bf_rne(x.y), h2 = f2bf_rne(x.z), h3 = f2bf_rne(x.w);
    ushort4 hv = { h0, h1, h2, h3 };
    ushort4 lv = { f2bf_rne(x.x - bf2f(h0)), f2bf_rne(x.y - bf2f(h1)),
                   f2bf_rne(x.z - bf2f(h2)), f2bf_rne(x.w - bf2f(h3)) };
    ((ushort4*)hi)[t] = hv;
    ((ushort4*)lo)[t] = lv;
}

// ---- build W^T = [Wm1|Ws1]^T as bf16 hi/lo, layout [n][k] ------------------
__global__ void k_split_w(const float* __restrict__ Wm1, const float* __restrict__ Ws1,
                          u16* __restrict__ whi, u16* __restrict__ wlo) {
    int t = blockIdx.x * 256 + threadIdx.x;           // t < 256*512
    int n = t >> 9, k = t & 511;
    float v = (n < HH) ? Wm1[k * HH + n] : Ws1[k * HH + (n - HH)];
    u16 h = f2bf_rne(v);
    whi[t] = h;
    wlo[t] = f2bf_rne(v - bf2f(h));
}

// ---- GEMM: P[M=100096p,256] = A[M,512] @ W[512,256] ------------------------
__global__ __launch_bounds__(256) void k_gemm(
        const u16* __restrict__ Ahi, const u16* __restrict__ Alo,
        const u16* __restrict__ Bhi, const u16* __restrict__ Blo,
        float* __restrict__ P) {
    __shared__ u16 lds[4][4096];   // 0=Ahi 1=Alo 2=Bhi 3=Blo, each 128x32 bf16

    const int tid  = threadIdx.x;
    const int wave = tid >> 6, lane = tid & 63;
    const int ml = lane & 15, quad = lane >> 4;
    const int rowBase = blockIdx.y * 128;
    const int colBase = blockIdx.x * 128;
    const bool SIG = (blockIdx.x == 1);
    const int waveRow = (wave & 1) * 64, waveCol = (wave >> 1) * 64;

    floatx4 acc[4][4];
#pragma unroll
    for (int i = 0; i < 4; i++)
#pragma unroll
        for (int j = 0; j < 4; j++) acc[i][j] = (floatx4){0.f, 0.f, 0.f, 0.f};

    const int r0 = tid >> 2, ko = (tid & 3) * 8;
    const u16* gA0  = Ahi + (size_t)(rowBase + r0) * FF + ko;
    const u16* gA1  = gA0 + (size_t)64 * FF;
    const u16* gAl0 = Alo + (size_t)(rowBase + r0) * FF + ko;
    const u16* gAl1 = gAl0 + (size_t)64 * FF;
    const u16* gB0  = Bhi + (size_t)(colBase + r0) * FF + ko;
    const u16* gB1  = gB0 + (size_t)64 * FF;
    const u16* gBl0 = Blo + (size_t)(colBase + r0) * FF + ko;
    const u16* gBl1 = gBl0 + (size_t)64 * FF;
    const int ldst0 = wave * 512;
    const int ldst1 = 2048 + wave * 512;

    const int aoff = (waveRow + ml) * 32 + quad * 8;
    const int boff = (waveCol + ml) * 32 + quad * 8;

    for (int kt = 0; kt < FF; kt += 32) {
        __syncthreads();
        async16(gA0 + kt, &lds[0][ldst0]);
        async16(gA1 + kt, &lds[0][ldst1]);
        async16(gB0 + kt, &lds[2][ldst0]);
        async16(gB1 + kt, &lds[2][ldst1]);
        if (SIG) {
            async16(gAl0 + kt, &lds[1][ldst0]);
            async16(gAl1 + kt, &lds[1][ldst1]);
            async16(gBl0 + kt, &lds[3][ldst0]);
            async16(gBl1 + kt, &lds[3][ldst1]);
        }
        __syncthreads();

        short8 ah[4], bh[4];
#pragma unroll
        for (int i = 0; i < 4; i++) ah[i] = *(const short8*)&lds[0][aoff + i * 512];
#pragma unroll
        for (int j = 0; j < 4; j++) bh[j] = *(const short8*)&lds[2][boff + j * 512];

        if (!SIG) {
#pragma unroll
            for (int i = 0; i < 4; i++)
#pragma unroll
                for (int j = 0; j < 4; j++)
                    acc[i][j] = __builtin_amdgcn_mfma_f32_16x16x32_bf16(
                        ah[i], bh[j], acc[i][j], 0, 0, 0);
        } else {
            short8 al[4], bl[4];
#pragma unroll
            for (int i = 0; i < 4; i++) al[i] = *(const short8*)&lds[1][aoff + i * 512];
#pragma unroll
            for (int j = 0; j < 4; j++) bl[j] = *(const short8*)&lds[3][boff + j * 512];
#pragma unroll
            for (int i = 0; i < 4; i++)
#pragma unroll
                for (int j = 0; j < 4; j++) {
                    floatx4 c = acc[i][j];
                    c = __builtin_amdgcn_mfma_f32_16x16x32_bf16(ah[i], bh[j], c, 0, 0, 0);
                    c = __builtin_amdgcn_mfma_f32_16x16x32_bf16(ah[i], bl[j], c, 0, 0, 0);
                    c = __builtin_amdgcn_mfma_f32_16x16x32_bf16(al[i], bh[j], c, 0, 0, 0);
                    acc[i][j] = c;
                }
        }
    }

#pragma unroll
    for (int i = 0; i < 4; i++) {
        int rb = rowBase + waveRow + i * 16 + quad * 4;
#pragma unroll
        for (int j = 0; j < 4; j++) {
            int col = colBase + waveCol + j * 16 + ml;
#pragma unroll
            for (int r = 0; r < 4; r++) {
                int row = rb + r;
                if (row < NN) P[(size_t)row * 256 + col] = acc[i][j][r];
            }
        }
    }
}

// ---- epilogue: activations + small GEMMs -> Z interleaved [node][16] -------
// Z[i][0..7] = Zm (miu path), Z[i][8..15] = Zs (sigma path)
__global__ __launch_bounds__(256) void k_epi(const float* __restrict__ P,
        const float* __restrict__ Wm2, const float* __restrict__ Ws2,
        float* __restrict__ Z) {
    __shared__ float xm[32 * 128];
    __shared__ float xs[32 * 128];
    __shared__ float wl[2048];
    const int tid = threadIdx.x;
    const int r0 = blockIdx.x * 32;

    for (int i = tid; i < 2048; i += 256) wl[i] = (i < 1024) ? Wm2[i] : Ws2[i - 1024];

#pragma unroll
    for (int p = 0; p < 16; ++p) {
        int idx = p * 256 + tid;            // 0..4095 = 32 rows x 128 k
        int r = idx >> 7, k = idx & 127;
        float u = P[(size_t)(r0 + r) * 256 + k];
        float v = P[(size_t)(r0 + r) * 256 + 128 + k];
        float m1 = u > 0.f ? u : __expf(u) - 1.f;   // elu
        float s1 = v > 0.f ? v : 0.f;               // relu
        float a1 = __expf(-s1);                     // exp(-gamma*sigma1)
        xm[idx] = m1 * a1;
        xs[idx] = s1 * a1 * a1;
    }
    __syncthreads();

#pragma unroll
    for (int p = 0; p < 2; ++p) {
        int task = p * 256 + tid;           // 0..511 = 32 rows x 16 outputs
        int r = task >> 4, oc = task & 15;
        const float* xv = (oc < 8) ? &xm[r * 128] : &xs[r * 128];
        const float* wv = &wl[(oc < 8) ? 0 : 1024];
        int c = oc & 7;
        float acc = 0.f;
#pragma unroll 8
        for (int k = 0; k < 128; ++k) acc += xv[k] * wv[k * 8 + c];
        int row = r0 + r;
        Z[row * 16 + ((oc < 8) ? c : 8 + c)] = acc;
    }
}

// ================= CSR build =================================================
__global__ void k_deg(const int* __restrict__ dst, int* __restrict__ deg) {
    int e = blockIdx.x * 256 + threadIdx.x;    // grid covers EE exactly
    atomicAdd(&deg[dst[e]], 1);
}

__global__ void k_scan1(const int* __restrict__ deg, int* __restrict__ bsum) {
    int t = threadIdx.x;
    int4 v = ((const int4*)deg)[blockIdx.x * 256 + t];
    __shared__ int red[256];
    red[t] = v.x + v.y + v.z + v.w;
    __syncthreads();
    for (int o = 128; o > 0; o >>= 1) {
        if (t < o) red[t] += red[t + o];
        __syncthreads();
    }
    if (t == 0) bsum[blockIdx.x] = red[0];
}

__global__ void k_scan2(const int* __restrict__ bsum, int* __restrict__ boff) {
    int t = threadIdx.x;                       // 128 threads
    __shared__ int s[128];
    int own = (t < NB) ? bsum[t] : 0;
    s[t] = own;
    __syncthreads();
    for (int o = 1; o < 128; o <<= 1) {
        int v = (t >= o) ? s[t - o] : 0;
        __syncthreads();
        s[t] += v;
        __syncthreads();
    }
    if (t < NB) boff[t] = s[t] - own;          // exclusive
}

__global__ void k_scan3(const int* __restrict__ deg, const int* __restrict__ boff,
                        int* __restrict__ ptr, int* __restrict__ cursor) {
    int t = threadIdx.x;
    int gi = blockIdx.x * 256 + t;
    int4 v = ((const int4*)deg)[gi];
    int tsum = v.x + v.y + v.z + v.w;
    __shared__ int s[256];
    s[t] = tsum;
    __syncthreads();
    for (int o = 1; o < 256; o <<= 1) {
        int pv = (t >= o) ? s[t - o] : 0;
        __syncthreads();
        s[t] += pv;
        __syncthreads();
    }
    int base = boff[blockIdx.x] + (s[t] - tsum);
    int4 e;
    e.x = base;
    e.y = base + v.x;
    e.z = e.y + v.y;
    e.w = e.z + v.z;
    ((int4*)ptr)[gi] = e;
    ((int4*)cursor)[gi] = e;
}

__global__ void k_scatter(const int* __restrict__ src, const int* __restrict__ dst,
                          const float* __restrict__ w1, const float* __restrict__ w2,
                          int* __restrict__ cursor, int4* __restrict__ payload) {
    int e = blockIdx.x * 256 + threadIdx.x;
    int d = dst[e];
    int p = atomicAdd(&cursor[d], 1);
    int4 pl;
    pl.x = src[e];
    pl.y = __builtin_bit_cast(int, w1[e]);
    pl.z = __builtin_bit_cast(int, w2[e]);
    pl.w = 0;
    payload[p] = pl;
}

// ---- agg1 (CSR): hm[i][c] = sum w1*Zm[src][c]; hs[i][c] = sum w2*Zs[src][c]
// one wave per node: 8 edge slots x 8 channels
__global__ __launch_bounds__(256) void k_aggA(const int* __restrict__ ptr,
        const int4* __restrict__ payload, const float* __restrict__ Z,
        float* __restrict__ hm, float* __restrict__ hs) {
    int wave = threadIdx.x >> 6, lane = threadIdx.x & 63;
    int i = blockIdx.x * 4 + wave;
    if (i >= NN) return;
    int er = lane >> 3, c = lane & 7;
    int start = ptr[i], end = ptr[i + 1];
    float am = 0.f, as_ = 0.f;
    for (int j = start + er; j < end; j += 8) {
        int4 p = payload[j];
        float w1 = __builtin_bit_cast(float, p.y);
        float w2 = __builtin_bit_cast(float, p.z);
        const float* zr = Z + (size_t)p.x * 16;
        am  += w1 * zr[c];
        as_ += w2 * zr[8 + c];
    }
    am  += __shfl_xor(am, 8, 64);
    am  += __shfl_xor(am, 16, 64);
    am  += __shfl_xor(am, 32, 64);
    as_ += __shfl_xor(as_, 8, 64);
    as_ += __shfl_xor(as_, 16, 64);
    as_ += __shfl_xor(as_, 32, 64);
    if (lane < 8) {
        hm[i * 8 + lane] = am;
        hs[i * 8 + lane] = as_;
    }
}

// ---- node transform: y = elu(hm)*exp(-relu(hs)); out-base = noise*sqrt -----
__global__ void k_node(const float* __restrict__ hm, const float* __restrict__ hs,
        const float* __restrict__ noise, float* __restrict__ y,
        float* __restrict__ out) {
    int t = blockIdx.x * 256 + threadIdx.x;   // < NN*8
    float m = hm[t], s = hs[t];
    float miu2 = m > 0.f ? m : __expf(m) - 1.f;
    float s2 = s > 0.f ? s : 0.f;
    y[t] = miu2 * __expf(-s2);
    out[t] = noise[t] * sqrtf(s2 + 1e-8f);
}

// ---- agg2 (CSR): out[i][c] += sum w1*y[src][c] -----------------------------
__global__ __launch_bounds__(256) void k_aggB(const int* __restrict__ ptr,
        const int4* __restrict__ payload, const float* __restrict__ y,
        float* __restrict__ out) {
    int wave = threadIdx.x >> 6, lane = threadIdx.x & 63;
    int i = blockIdx.x * 4 + wave;
    if (i >= NN) return;
    int er = lane >> 3, c = lane & 7;
    int start = ptr[i], end = ptr[i + 1];
    float acc = 0.f;
    for (int j = start + er; j < end; j += 8) {
        int4 p = payload[j];
        float w1 = __builtin_bit_cast(float, p.y);
        acc += w1 * y[(size_t)p.x * 8 + c];
    }
    acc += __shfl_xor(acc, 8, 64);
    acc += __shfl_xor(acc, 16, 64);
    acc += __shfl_xor(acc, 32, 64);
    if (lane < 8) out[i * 8 + lane] += acc;
}

extern "C" void kernel_launch(void* const* d_in, const int* in_sizes, int n_in,
                              void* d_out, int out_size, void* d_ws, size_t ws_size,
                              hipStream_t stream) {
    (void)in_sizes; (void)n_in; (void)out_size; (void)ws_size;
    const float* feat  = (const float*)d_in[0];
    const int*   esrc  = (const int*)d_in[1];
    const int*   edst  = (const int*)d_in[2];
    const float* w1    = (const float*)d_in[3];
    const float* w2    = (const float*)d_in[4];
    const float* Wm1   = (const float*)d_in[5];
    const float* Ws1   = (const float*)d_in[6];
    const float* Wm2   = (const float*)d_in[7];
    const float* Ws2   = (const float*)d_in[8];
    const float* noise = (const float*)d_in[9];
    float* out = (float*)d_out;

    char* ws = (char*)d_ws;
    size_t off = 0;
    auto alloc = [&](size_t bytes) -> void* {
        void* p = ws + off;
        off += (bytes + 255) & ~(size_t)255;
        return p;
    };
    u16*   Ahi  = (u16*)alloc((size_t)PADM * FF * 2);
    u16*   Alo  = (u16*)alloc((size_t)PADM * FF * 2);
    u16*   WhiT = (u16*)alloc((size_t)256 * 512 * 2);
    u16*   WloT = (u16*)alloc((size_t)256 * 512 * 2);
    float* P    = (float*)alloc((size_t)PADM * 256 * 4);
    float* Z    = (float*)alloc((size_t)NN * 16 * 4);
    float* hm   = (float*)alloc((size_t)NN * 8 * 4);
    float* hs   = (float*)alloc((size_t)NN * 8 * 4);
    float* yb   = (float*)alloc((size_t)NN * 8 * 4);
    int*   deg  = (int*)alloc((size_t)NPAD * 4);
    int*   ptr  = (int*)alloc((size_t)(NPAD + 4) * 4);
    int*   cur  = (int*)alloc((size_t)NPAD * 4);
    int*   bsum = (int*)alloc(256 * 4);
    int*   boff = (int*)alloc(256 * 4);
    int4*  pay  = (int4*)alloc((size_t)EE * 16);

    hipMemsetAsync(deg, 0, (size_t)NPAD * 4, stream);

    // CSR build (cheap, overlapped-in-order on the stream)
    k_deg    <<<EE / 256, 256, 0, stream>>>(edst, deg);
    k_scan1  <<<NB, 256, 0, stream>>>(deg, bsum);
    k_scan2  <<<1, 128, 0, stream>>>(bsum, boff);
    k_scan3  <<<NB, 256, 0, stream>>>(deg, boff, ptr, cur);
    k_scatter<<<EE / 256, 256, 0, stream>>>(esrc, edst, w1, w2, cur, pay);

    // dense pipeline
    k_split_a<<<NN * FF / 4 / 256, 256, 0, stream>>>(feat, Ahi, Alo);
    k_split_w<<<512, 256, 0, stream>>>(Wm1, Ws1, WhiT, WloT);
    k_gemm   <<<dim3(2, PADM / 128), 256, 0, stream>>>(Ahi, Alo, WhiT, WloT, P);
    k_epi    <<<NN / 32, 256, 0, stream>>>(P, Wm2, Ws2, Z);

    // aggregation, atomic-free
    k_aggA<<<(NN + 3) / 4, 256, 0, stream>>>(ptr, pay, Z, hm, hs);
    k_node<<<NN * 8 / 256, 256, 0, stream>>>(hm, hs, noise, yb, out);
    k_aggB<<<(NN + 3) / 4, 256, 0, stream>>>(ptr, pay, yb, out);
}